// Round 8
// baseline (32609.912 us; speedup 1.0000x reference)
//
#include <hip/hip_runtime.h>

// Custom LSTM scan.  B=64, L=512, P=64, A=16, D=512, F=80.
//   h_t = h_{t-1} + tanh(x_t W_ci + b_ci) * sigmoid(h_{t-1} R_ig + b_ig)
// Round 8: 4-way k-split, cooperative launch (256 WGs, 1/CU).  WG q of row b
// computes partial z_q[d] over k in [q*128,(q+1)*128); R share fully
// register-resident (16 uint4 f16-pair chunks = 64 VGPRs).  Partials
// exchanged via IC with DOUBLE-BUFFERED slots (parity of t) + step flags —
// round 7's single-buffer version had an overwrite race (absmax 0.56).
// All 4 WGs redundantly compute the h update; q==0 does the out-projection.

#define B_  64
#define L_  512
#define P_  64
#define A_  16
#define D_  512
#define F_  80
#define CI_R 8
#define NQ  4

typedef _Float16 half2_t __attribute__((ext_vector_type(2)));

__device__ __forceinline__ float dot2(unsigned int r, unsigned int h, float acc) {
    return __builtin_amdgcn_fdot2(__builtin_bit_cast(half2_t, h),
                                  __builtin_bit_cast(half2_t, r), acc, false);
}
template<int CTRL>
__device__ __forceinline__ float dpp_mov(float v) {
    return __builtin_bit_cast(float, __builtin_amdgcn_update_dpp(
        0, __builtin_bit_cast(int, v), CTRL, 0xF, 0xF, true));
}
// DPP ctrls: quad_perm(1,0,3,2)=0xB1 (xor1), quad_perm(2,3,0,1)=0x4E (xor2),
// row_half_mirror=0x141, row_mirror=0x140, row_bcast15=0x142, row_bcast31=0x143.

// Pack R_ig fp32[k][d] -> f16-pair chunks: uint4 chunk (q,c,d) holds pairs
// p=4c..4c+3 (k = q*128+2p, 2p+1) of column d.
__global__ __launch_bounds__(256) void prep_kernel(const float* __restrict__ R,
                                                   unsigned int* __restrict__ Rp) {
    int id = blockIdx.x * 256 + threadIdx.x;          // 131072 uints
    int e = id & 3;
    int d = (id >> 2) & (D_ - 1);
    int c = (id >> 11) & 15;
    int q = id >> 15;
    int p = 4 * c + e;
    int k0 = q * 128 + 2 * p;
    half2_t v;
    v.x = (_Float16)R[k0 * D_ + d];
    v.y = (_Float16)R[(k0 + 1) * D_ + d];
    Rp[id] = __builtin_bit_cast(unsigned int, v);
}

// ci = tanh(x @ W_ci + b_ci), stored f16.
__global__ __launch_bounds__(256) void ci_kernel(const float* __restrict__ obs,
                                                 const float* __restrict__ act,
                                                 const float* __restrict__ W,
                                                 const float* __restrict__ bci,
                                                 unsigned short* __restrict__ ci) {
    __shared__ float xs[CI_R][F_];
    int row0 = blockIdx.x * CI_R;
    int tid = threadIdx.x;
    for (int idx = tid; idx < CI_R * F_; idx += 256) {
        int r = idx / F_, f = idx % F_;
        float v = (f < P_) ? obs[(size_t)(row0 + r) * P_ + f]
                           : act[(size_t)(row0 + r) * A_ + (f - P_)];
        xs[r][f] = v;
    }
    __syncthreads();
    int d0 = tid, d1 = tid + 256;
    float a0[CI_R], a1[CI_R];
    #pragma unroll
    for (int r = 0; r < CI_R; ++r) { a0[r] = 0.f; a1[r] = 0.f; }
    for (int f = 0; f < F_; ++f) {
        float w0 = W[f * D_ + d0];
        float w1 = W[f * D_ + d1];
        #pragma unroll
        for (int r = 0; r < CI_R; ++r) {
            float xv = xs[r][f];
            a0[r] += xv * w0;
            a1[r] += xv * w1;
        }
    }
    float b0 = bci[d0], b1 = bci[d1];
    #pragma unroll
    for (int r = 0; r < CI_R; ++r) {
        float z0 = a0[r] + b0, z1 = a1[r] + b1;
        float e0 = __expf(-2.f * __builtin_fabsf(z0));
        float e1 = __expf(-2.f * __builtin_fabsf(z1));
        float m0 = (1.f - e0) * __builtin_amdgcn_rcpf(1.f + e0);
        float m1 = (1.f - e1) * __builtin_amdgcn_rcpf(1.f + e1);
        float t0 = z0 < 0.f ? -m0 : m0;
        float t1 = z1 < 0.f ? -m1 : m1;
        ci[(size_t)(row0 + r) * D_ + d0] = __builtin_bit_cast(unsigned short, (_Float16)t0);
        ci[(size_t)(row0 + r) * D_ + d1] = __builtin_bit_cast(unsigned short, (_Float16)t1);
    }
}

__global__ __launch_bounds__(256) void initflags_kernel(unsigned int* __restrict__ flags) {
    flags[threadIdx.x] = 0u;          // NQ*B_ = 256 flags
}

// Scan: blockIdx = q*64 + b.  Thread d=tid owns output/h element d.
__global__ __launch_bounds__(512)
__attribute__((amdgpu_waves_per_eu(2, 2)))
void scan_kernel(const uint4* __restrict__ Rp, const unsigned short* __restrict__ ci,
                 const float* __restrict__ b_ig, const float* __restrict__ W_out,
                 const float* __restrict__ b_out, float* __restrict__ Zb,
                 unsigned int* __restrict__ flags, float* __restrict__ out)
{
    const int tid = threadIdx.x;
    const int bi = blockIdx.x;
    const int q = bi >> 6;
    const int b = bi & 63;
    const int w = tid >> 6;
    const int l = tid & 63;

    __shared__ unsigned int hpair[64];   // packed f16 h slice (128 values)
    __shared__ float red[8];
    __shared__ float outbuf[L_];

    // register-resident R: chunk c at uint4 index q*8192 + c*512 + tid
    const uint4* tb = Rp + (q << 13) + tid;
    uint4 rr[16];
    #pragma unroll
    for (int c = 0; c < 16; ++c) rr[c] = tb[c * 512];
    #pragma unroll
    for (int c = 0; c < 16; ++c)
        asm volatile("" : "+v"(rr[c].x), "+v"(rr[c].y), "+v"(rr[c].z), "+v"(rr[c].w));

    float hval = 0.f;
    const float bg = b_ig[tid];
    const float wo = W_out[tid];
    const float bo = b_out[0];
    const unsigned short* cip = ci + (size_t)b * L_ * D_ + tid;
    // double-buffered exchange: Zrow0[parity*NQ*D + q*D + tid]
    float* Zrow0 = Zb + b * (2 * NQ * D_);
    unsigned int* flagrow = flags + b * NQ;

    unsigned int hs[64];                 // h-pair slice (wave-uniform)
    #pragma unroll
    for (int p = 0; p < 64; ++p) hs[p] = 0u;

    __syncthreads();

    #pragma unroll 1
    for (int t = 0; t < L_; ++t) {
        unsigned short cu = cip[t * D_];              // prefetch ci

        float acc0 = 0.f, acc1 = 0.f;
        #pragma unroll
        for (int c = 0; c < 8; ++c) {
            acc0 = dot2(rr[c].x, hs[4 * c + 0], acc0);
            acc0 = dot2(rr[c].y, hs[4 * c + 1], acc0);
            acc0 = dot2(rr[c].z, hs[4 * c + 2], acc0);
            acc0 = dot2(rr[c].w, hs[4 * c + 3], acc0);
        }
        #pragma unroll
        for (int c = 8; c < 16; ++c) {
            acc1 = dot2(rr[c].x, hs[4 * c + 0], acc1);
            acc1 = dot2(rr[c].y, hs[4 * c + 1], acc1);
            acc1 = dot2(rr[c].z, hs[4 * c + 2], acc1);
            acc1 = dot2(rr[c].w, hs[4 * c + 3], acc1);
        }
        float acc = acc0 + acc1;

        float* Zcur = Zrow0 + (t & 1) * (NQ * D_);

        // publish partial into parity buffer
        __hip_atomic_store(&Zcur[q * D_ + tid], acc, __ATOMIC_RELAXED,
                           __HIP_MEMORY_SCOPE_AGENT);
        __threadfence();
        __syncthreads();                              // B1: all stores done
        if (tid == 0)
            __hip_atomic_store(&flagrow[q], (unsigned)(t + 1), __ATOMIC_RELEASE,
                               __HIP_MEMORY_SCOPE_AGENT);
        if (tid < NQ - 1) {
            int peer = tid + (tid >= q ? 1 : 0);
            while (__hip_atomic_load(&flagrow[peer], __ATOMIC_ACQUIRE,
                                     __HIP_MEMORY_SCOPE_AGENT) < (unsigned)(t + 1)) {}
        }
        __threadfence();
        __syncthreads();                              // B2: peers ready

        float z = acc + bg;
        #pragma unroll
        for (int i = 0; i < NQ - 1; ++i) {
            int peer = i + (i >= q ? 1 : 0);
            z += __hip_atomic_load(&Zcur[peer * D_ + tid], __ATOMIC_RELAXED,
                                   __HIP_MEMORY_SCOPE_AGENT);
        }

        float ig = __builtin_amdgcn_rcpf(1.f + __expf(-z));
        float civ = (float)__builtin_bit_cast(_Float16, cu);
        hval += civ * ig;

        float nbh = dpp_mov<0xB1>(hval);              // h[tid^1]

        if (q == 0) {                                 // out-projection
            float po = hval * wo;
            po += dpp_mov<0xB1>(po);
            po += dpp_mov<0x4E>(po);
            po += dpp_mov<0x141>(po);
            po += dpp_mov<0x140>(po);
            po += dpp_mov<0x142>(po);
            po += dpp_mov<0x143>(po);
            if (l == 63) red[w] = po;
        }
        // write new h slice pairs (threads of slice q only, even lanes)
        if (((tid >> 7) == q) && !(tid & 1)) {
            hpair[(tid & 127) >> 1] = __builtin_bit_cast(unsigned int,
                __builtin_amdgcn_cvt_pkrtz(hval, nbh));
        }
        __syncthreads();                              // B3: hpair/red visible

        unsigned int hv = hpair[l];                   // pair l -> lane l
        #pragma unroll
        for (int p = 0; p < 64; ++p)
            hs[p] = (unsigned int)__builtin_amdgcn_readlane((int)hv, p);

        if (q == 0 && tid == 0) {
            outbuf[t] = red[0] + red[1] + red[2] + red[3] +
                        red[4] + red[5] + red[6] + red[7] + bo;
        }
    }
    __syncthreads();
    if (q == 0) out[b * L_ + tid] = outbuf[tid];
}

extern "C" void kernel_launch(void* const* d_in, const int* in_sizes, int n_in,
                              void* d_out, int out_size, void* d_ws, size_t ws_size,
                              hipStream_t stream) {
    const float* obs   = (const float*)d_in[0];
    const float* act   = (const float*)d_in[1];
    const float* W_ci  = (const float*)d_in[2];
    const float* b_ci  = (const float*)d_in[3];
    const float* R_ig  = (const float*)d_in[4];
    const float* b_ig  = (const float*)d_in[5];
    const float* W_out = (const float*)d_in[6];
    const float* b_out = (const float*)d_in[7];
    float* out = (float*)d_out;

    char* ws = (char*)d_ws;
    size_t off_ci = 0;
    size_t off_Rp = (size_t)B_ * L_ * D_ * 2;           // 32 MB
    size_t off_Zb = off_Rp + 524288;                    // + 512 KB
    size_t off_fl = off_Zb + (size_t)B_ * 2 * NQ * D_ * 4;  // + 1 MB
    unsigned short* ci  = (unsigned short*)(ws + off_ci);
    unsigned int* Rp    = (unsigned int*)(ws + off_Rp);
    float* Zb           = (float*)(ws + off_Zb);
    unsigned int* flags = (unsigned int*)(ws + off_fl);

    prep_kernel<<<512, 256, 0, stream>>>(R_ig, Rp);
    ci_kernel<<<(B_ * L_) / CI_R, 256, 0, stream>>>(obs, act, W_ci, b_ci, ci);
    initflags_kernel<<<1, 256, 0, stream>>>(flags);

    const uint4* Rp4 = (const uint4*)Rp;
    void* args[] = {(void*)&Rp4, (void*)&ci, (void*)&b_ig, (void*)&W_out,
                    (void*)&b_out, (void*)&Zb, (void*)&flags, (void*)&out};
    hipLaunchCooperativeKernel((void*)scan_kernel, dim3(NQ * B_), dim3(D_),
                               args, 0, stream);
}

// Round 9
// 1140.810 us; speedup vs baseline: 28.5849x; 28.5849x over previous
//
#include <hip/hip_runtime.h>

// Custom LSTM scan.  B=64, L=512, P=64, A=16, D=512, F=80.
//   h_t = h_{t-1} + tanh(x_t W_ci + b_ci) * sigmoid(h_{t-1} R_ig + b_ig)
// Round 9: back to intra-CU scan (r8's cross-WG exchange hit HBM: 266 MB
// writes, 60-140 us/step).  One WG (512 thr) per batch row.  Output d by
// 8 lanes (k-slices of 64) reduced via DPP.  R chunks jc=0..63 per thread:
// 0..39 register-pinned, 40..51 dynamic LDS (96 KB), 52..63 L2-streamed.
// Single barrier per step: h-broadcast + red[] parity double-buffered.

#define B_  64
#define L_  512
#define P_  64
#define A_  16
#define D_  512
#define F_  80
#define CI_R 8

#define NLDS 12
#define SMEM_BYTES (NLDS * D_ * 16 + 2048 + 64 + 2048)

typedef _Float16 half2_t __attribute__((ext_vector_type(2)));

__device__ __forceinline__ float dot2(unsigned int r, unsigned int h, float acc) {
    return __builtin_amdgcn_fdot2(__builtin_bit_cast(half2_t, h),
                                  __builtin_bit_cast(half2_t, r), acc, false);
}
__device__ __forceinline__ float dot4u(uint4 r, uint4 h, float acc) {
    acc = dot2(r.x, h.x, acc);
    acc = dot2(r.y, h.y, acc);
    acc = dot2(r.z, h.z, acc);
    acc = dot2(r.w, h.w, acc);
    return acc;
}
template<int CTRL>
__device__ __forceinline__ float dpp_mov(float v) {
    return __builtin_bit_cast(float, __builtin_amdgcn_update_dpp(
        0, __builtin_bit_cast(int, v), CTRL, 0xF, 0xF, true));
}
// DPP: quad_perm(1,0,3,2)=0xB1 xor1; quad_perm(2,3,0,1)=0x4E xor2;
// row_half_mirror=0x141 xor7; row_mirror=0x140; row_bcast15=0x142; row_bcast31=0x143.

// Pack R_ig fp32[k][d] -> f16-pair uint chunks [w][jc][l][q]:
// uint4 (w,jc,l), j=jc>>3, c=jc&7, holds pairs p=g*32+c*4+{0..3}
// (k=2p,2p+1) of column d = w*64 + (l>>3)*8 + j, g=l&7.
__global__ __launch_bounds__(256) void prep_kernel(const float* __restrict__ R,
                                                   unsigned int* __restrict__ Rp) {
    int id = blockIdx.x * 256 + threadIdx.x;          // 131072 uints
    int q = id & 3;
    int l = (id >> 2) & 63;
    int c = (id >> 8) & 7;
    int j = (id >> 11) & 7;
    int w = id >> 14;
    int r = l >> 3, g = l & 7;
    int d = w * 64 + r * 8 + j;
    int p = g * 32 + c * 4 + q;
    int k0 = 2 * p;
    half2_t v;
    v.x = (_Float16)R[k0 * D_ + d];
    v.y = (_Float16)R[(k0 + 1) * D_ + d];
    Rp[id] = __builtin_bit_cast(unsigned int, v);
}

// ci = tanh(x @ W_ci + b_ci), stored f16.
__global__ __launch_bounds__(256) void ci_kernel(const float* __restrict__ obs,
                                                 const float* __restrict__ act,
                                                 const float* __restrict__ W,
                                                 const float* __restrict__ bci,
                                                 unsigned short* __restrict__ ci) {
    __shared__ float xs[CI_R][F_];
    int row0 = blockIdx.x * CI_R;
    int tid = threadIdx.x;
    for (int idx = tid; idx < CI_R * F_; idx += 256) {
        int r = idx / F_, f = idx % F_;
        float v = (f < P_) ? obs[(size_t)(row0 + r) * P_ + f]
                           : act[(size_t)(row0 + r) * A_ + (f - P_)];
        xs[r][f] = v;
    }
    __syncthreads();
    int d0 = tid, d1 = tid + 256;
    float a0[CI_R], a1[CI_R];
    #pragma unroll
    for (int r = 0; r < CI_R; ++r) { a0[r] = 0.f; a1[r] = 0.f; }
    for (int f = 0; f < F_; ++f) {
        float w0 = W[f * D_ + d0];
        float w1 = W[f * D_ + d1];
        #pragma unroll
        for (int r = 0; r < CI_R; ++r) {
            float xv = xs[r][f];
            a0[r] += xv * w0;
            a1[r] += xv * w1;
        }
    }
    float b0 = bci[d0], b1 = bci[d1];
    #pragma unroll
    for (int r = 0; r < CI_R; ++r) {
        float z0 = a0[r] + b0, z1 = a1[r] + b1;
        float e0 = __expf(-2.f * __builtin_fabsf(z0));
        float e1 = __expf(-2.f * __builtin_fabsf(z1));
        float m0 = (1.f - e0) * __builtin_amdgcn_rcpf(1.f + e0);
        float m1 = (1.f - e1) * __builtin_amdgcn_rcpf(1.f + e1);
        float t0 = z0 < 0.f ? -m0 : m0;
        float t1 = z1 < 0.f ? -m1 : m1;
        ci[(size_t)(row0 + r) * D_ + d0] = __builtin_bit_cast(unsigned short, (_Float16)t0);
        ci[(size_t)(row0 + r) * D_ + d1] = __builtin_bit_cast(unsigned short, (_Float16)t1);
    }
}

// Serial scan.  One block per batch row.  Thread (w=tid>>6, l=tid&63), g=l&7:
// partials over k in [g*64,g*64+64) for outputs d = w*64+(l>>3)*8+j, j=0..7;
// DPP reduce-scatter -> thread owns d=tid.  jc map: 0..39 rr, 40..51 ldsR,
// 52..57 stream A, 58..63 stream B (shared 6-chunk buffer).
__global__ __launch_bounds__(512)
__attribute__((amdgpu_waves_per_eu(2, 2)))
void scan_kernel(
    const uint4* __restrict__ Rp, const unsigned short* __restrict__ ci,
    const float* __restrict__ b_ig, const float* __restrict__ W_out,
    const float* __restrict__ b_out, float* __restrict__ out)
{
    const int tid = threadIdx.x;
    const int b = blockIdx.x;
    const int w = tid >> 6;
    const int l = tid & 63;
    const int g = l & 7;

    extern __shared__ __align__(16) char smem[];
    uint4* ldsR = (uint4*)smem;                                     // 12*512*16
    unsigned int* hpbuf = (unsigned int*)(smem + NLDS * D_ * 16);   // 2*1024 B
    float* redbuf = (float*)(smem + NLDS * D_ * 16 + 2048);         // 2*32 B
    float* outbuf = (float*)(smem + NLDS * D_ * 16 + 2112);         // 2048 B

    const uint4* tb = Rp + (w << 12) + l;   // chunk jc at tb[jc*64]

    // pin 40 chunks (jc 0..39, j=0..4) in VGPRs
    uint4 rr[40];
    #pragma unroll
    for (int i = 0; i < 40; ++i) rr[i] = tb[i * 64];
    #pragma unroll
    for (int i = 0; i < 40; ++i)
        asm volatile("" : "+v"(rr[i].x), "+v"(rr[i].y), "+v"(rr[i].z), "+v"(rr[i].w));

    #pragma unroll
    for (int i = 0; i < NLDS; ++i) ldsR[i * D_ + tid] = tb[(40 + i) * 64];
    if (tid < 256) hpbuf[tid] = 0u;        // h parity-buffer 0 = zeros

    float hval = 0.f;
    const float bg = b_ig[tid];
    const float wo = W_out[tid];
    const float bo = b_out[0];
    const unsigned short* cip = ci + (size_t)b * L_ * D_ + tid;

    // swizzled h write slot within a 256-uint buffer (conflict-free reads)
    const int wslot = (((w << 3) | ((((tid >> 3) & 7) + w) & 7)) << 2) | ((tid >> 1) & 3);

    __syncthreads();

    #pragma unroll 1
    for (int t = 0; t < L_; ++t) {
        const unsigned int* hpc = hpbuf + (t & 1) * 256;        // read buffer
        unsigned int* hpn = hpbuf + ((t & 1) ^ 1) * 256;        // write buffer
        float* redc = redbuf + (t & 1) * 8;

        // finish step t-1's output row (red of parity (t-1)&1, disjoint
        // from this epoch's red writes)
        if (t > 0 && tid == 0) {
            const float* rp = redbuf + ((t - 1) & 1) * 8;
            outbuf[t - 1] = rp[0] + rp[1] + rp[2] + rp[3] +
                            rp[4] + rp[5] + rp[6] + rp[7] + bo;
        }

        // issue stream group A (jc 52..57) + ci
        uint4 sb[6];
        #pragma unroll
        for (int i = 0; i < 6; ++i) sb[i] = tb[(52 + i) * 64];
        unsigned short cu = cip[t * D_];

        // h slice (8 uint4) from swizzled parity buffer
        const uint4* hp4s = (const uint4*)hpc;
        uint4 hsr[8];
        #pragma unroll
        for (int c = 0; c < 8; ++c) hsr[c] = hp4s[(g << 3) | ((c + g) & 7)];

        float p[8];
        #pragma unroll
        for (int j = 0; j < 8; ++j) p[j] = 0.f;

        // register chunks j=0,1 (covers A latency)
        #pragma unroll
        for (int i = 0; i < 16; ++i) p[i >> 3] = dot4u(rr[i], hsr[i & 7], p[i >> 3]);

        // consume A: jc52..55 -> p[6](c4..7); jc56,57 -> p[7](c0,1)
        #pragma unroll
        for (int i = 0; i < 4; ++i) p[6] = dot4u(sb[i], hsr[4 + i], p[6]);
        p[7] = dot4u(sb[4], hsr[0], p[7]);
        p[7] = dot4u(sb[5], hsr[1], p[7]);

        // issue stream group B (jc 58..63)
        #pragma unroll
        for (int i = 0; i < 6; ++i) sb[i] = tb[(58 + i) * 64];

        // register chunks j=2,3,4 (covers B latency)
        #pragma unroll
        for (int i = 16; i < 40; ++i) p[i >> 3] = dot4u(rr[i], hsr[i & 7], p[i >> 3]);

        // LDS chunks: jc40..47=(j5,c0..7) -> p[5]; jc48..51=(j6,c0..3) -> p[6]
        #pragma unroll
        for (int i = 0; i < 8; ++i) p[5] = dot4u(ldsR[i * D_ + tid], hsr[i], p[5]);
        #pragma unroll
        for (int i = 8; i < 12; ++i) p[6] = dot4u(ldsR[i * D_ + tid], hsr[i - 8], p[6]);

        // consume B: jc58..63 -> p[7](c2..7)
        #pragma unroll
        for (int i = 0; i < 6; ++i) p[7] = dot4u(sb[i], hsr[2 + i], p[7]);

        // DPP reduce-scatter across the 8-lane slice group
        float q0[4];
        #pragma unroll
        for (int i = 0; i < 4; ++i) {
            float a = p[i] + dpp_mov<0x141>(p[i]);       // xor7
            float c2 = p[i + 4] + dpp_mov<0x141>(p[i + 4]);
            q0[i] = (g & 4) ? c2 : a;
        }
        float r0a = q0[0] + dpp_mov<0xB1>(q0[0]);        // xor1
        float r0b = q0[1] + dpp_mov<0xB1>(q0[1]);
        float r1a = q0[2] + dpp_mov<0xB1>(q0[2]);
        float r1b = q0[3] + dpp_mov<0xB1>(q0[3]);
        float r0 = (g & 1) ? r0b : r0a;
        float r1 = (g & 1) ? r1b : r1a;
        float za = r0 + dpp_mov<0x4E>(r0);               // xor2
        float zb = r1 + dpp_mov<0x4E>(r1);
        float z = (g & 2) ? zb : za;                     // z for d = tid

        float zz = z + bg;
        float ig = __builtin_amdgcn_rcpf(1.f + __expf(-zz));
        float civ = (float)__builtin_bit_cast(_Float16, cu);
        hval += civ * ig;

        // out-projection partial (sum lands in lane 63)
        float po = hval * wo;
        po += dpp_mov<0xB1>(po);
        po += dpp_mov<0x4E>(po);
        po += dpp_mov<0x141>(po);
        po += dpp_mov<0x140>(po);
        po += dpp_mov<0x142>(po);
        po += dpp_mov<0x143>(po);

        float nbh = dpp_mov<0xB1>(hval);  // h[tid^1]

        // write new h into the parity write-buffer (disjoint from reads)
        if ((tid & 1) == 0) {
            hpn[wslot] = __builtin_bit_cast(unsigned int,
                             __builtin_amdgcn_cvt_pkrtz(hval, nbh));
        }
        if (l == 63) redc[w] = po;
        __syncthreads();                  // single barrier per step
    }
    if (tid == 0) {
        const float* rp = redbuf + ((L_ - 1) & 1) * 8;
        outbuf[L_ - 1] = rp[0] + rp[1] + rp[2] + rp[3] +
                         rp[4] + rp[5] + rp[6] + rp[7] + bo;
    }
    __syncthreads();
    out[b * L_ + tid] = outbuf[tid];
}

extern "C" void kernel_launch(void* const* d_in, const int* in_sizes, int n_in,
                              void* d_out, int out_size, void* d_ws, size_t ws_size,
                              hipStream_t stream) {
    const float* obs   = (const float*)d_in[0];
    const float* act   = (const float*)d_in[1];
    const float* W_ci  = (const float*)d_in[2];
    const float* b_ci  = (const float*)d_in[3];
    const float* R_ig  = (const float*)d_in[4];
    const float* b_ig  = (const float*)d_in[5];
    const float* W_out = (const float*)d_in[6];
    const float* b_out = (const float*)d_in[7];
    float* out = (float*)d_out;

    unsigned short* ci = (unsigned short*)d_ws;                        // 32 MB f16
    unsigned int* Rp = (unsigned int*)((char*)d_ws + (size_t)B_ * L_ * D_ * 2);

    hipFuncSetAttribute((const void*)scan_kernel,
                        hipFuncAttributeMaxDynamicSharedMemorySize, SMEM_BYTES);

    prep_kernel<<<512, 256, 0, stream>>>(R_ig, Rp);
    ci_kernel<<<(B_ * L_) / CI_R, 256, 0, stream>>>(obs, act, W_ci, b_ci, ci);
    scan_kernel<<<B_, D_, SMEM_BYTES, stream>>>((const uint4*)Rp, ci, b_ig, W_out, b_out, out);
}